// Round 15
// baseline (112.114 us; speedup 1.0000x reference)
//
#include <hip/hip_runtime.h>
#include <hip/hip_bf16.h>
#include <hip/hip_fp8.h>

// AlignConLoss: loss = sum_j [ log(sum_i exp(cn_i . an_j)) - cn_j . an_j ]
// B = 8192, D = 256, fp32 inputs, scalar fp32 out. sim in [-1,1] -> no max.
//
// R13 -> R14: back to the best structure (R11: C-panel in regs, LDS-staged
// A dbuf, counted-vmcnt barriers) with two occupancy/overhead levers:
//  1) LDS time-share: ONE 32 KB buffer holds the C-panel only until af is
//     captured to registers, then becomes the A double-buffer (barrier-
//     separated). 64->32 KB + __launch_bounds__(256,3) -> 3 waves/SIMD.
//  2) finalize folded into gemm via last-block counter (threadfence +
//     volatile colsum reads); counter zeroed by prep each launch.
// MX-fp8 mfma_scale 16x16x128 (scale=1.0), swizzle involution
// phys16B = log ^ (row&7) both sides — all R10/R11-verified (absmax 0).

#define BROWS 8192
#define DIM   256

typedef int   i32x4 __attribute__((ext_vector_type(4)));
typedef int   i32x8 __attribute__((ext_vector_type(8)));
typedef float f32x4 __attribute__((ext_vector_type(4)));

__device__ __forceinline__ void gload_lds16(const void* g, void* l) {
  __builtin_amdgcn_global_load_lds(
      (const __attribute__((address_space(1))) unsigned int*)g,
      (__attribute__((address_space(3))) unsigned int*)l, 16, 0, 0);
}

__device__ __forceinline__ unsigned char to_e4m3(float v) {
  __hip_fp8_e4m3 t(v);
  return *reinterpret_cast<unsigned char*>(&t);
}

// ---------------------------------------------------------------------------
// Kernel 1: per-row L2 norms -> fp8 e4m3 normalized An/Cn; exact fp32 diag.
// One wave per row. Blocks 0..31 zero colsum; block 0 zeroes the counter.
// ---------------------------------------------------------------------------
__global__ __launch_bounds__(256) void prep_kernel(
    const float* __restrict__ E1, const float* __restrict__ E2,
    unsigned char* __restrict__ An8, unsigned char* __restrict__ Cn8,
    float* __restrict__ diag, float* __restrict__ colsum,
    unsigned int* __restrict__ counter) {
  if (blockIdx.x < 32) colsum[blockIdx.x * 256 + threadIdx.x] = 0.f;
  if (blockIdx.x == 0 && threadIdx.x == 0) counter[0] = 0u;

  const int w    = threadIdx.x >> 6;
  const int lane = threadIdx.x & 63;
  const int row  = blockIdx.x * 4 + w;
  const size_t base = (size_t)row * DIM + lane * 4;

  const float4 a = *(const float4*)(E1 + base);
  const float4 c = *(const float4*)(E2 + base);

  float sa  = a.x*a.x + a.y*a.y + a.z*a.z + a.w*a.w;
  float sc  = c.x*c.x + c.y*c.y + c.z*c.z + c.w*c.w;
  float sac = a.x*c.x + a.y*c.y + a.z*c.z + a.w*c.w;
#pragma unroll
  for (int o = 32; o > 0; o >>= 1) {
    sa  += __shfl_down(sa,  o);
    sc  += __shfl_down(sc,  o);
    sac += __shfl_down(sac, o);
  }
  const float inva = 1.0f / fmaxf(sqrtf(__shfl(sa, 0)), 1e-8f);
  const float invc = 1.0f / fmaxf(sqrtf(__shfl(sc, 0)), 1e-8f);

  uchar4 pa, pc;
  pa.x = to_e4m3(a.x * inva); pa.y = to_e4m3(a.y * inva);
  pa.z = to_e4m3(a.z * inva); pa.w = to_e4m3(a.w * inva);
  pc.x = to_e4m3(c.x * invc); pc.y = to_e4m3(c.y * invc);
  pc.z = to_e4m3(c.z * invc); pc.w = to_e4m3(c.w * invc);
  *(uchar4*)(An8 + base) = pa;
  *(uchar4*)(Cn8 + base) = pc;
  if (lane == 0) diag[row] = sac * inva * invc;
}

// ---------------------------------------------------------------------------
// Kernel 2: block = 128 i x 512 j, grid = 64 x 16 = 1024. Waves (wr,wc) 2x2:
// 64 i-rows x 32 j-cols per jtile, 8 jtiles of 64 cols.
// Phase 1: C-panel -> lds[0..32K); vmcnt(0)+barrier; af -> 64 VGPR;
//          lgkmcnt(0)+barrier (C LDS dead).
// Phase 2: same 32 KB = A dbuf[2][16K]; R11 loop verbatim:
//   vmcnt{jj0:4, jj1:6, jj2-6:8, jj7:4} -> barrier -> ds_read bf ->
//   lgkmcnt(0) -> barrier -> stage(jj+2) -> 16 MFMA -> exp + 2 atomics.
// Tail: threadfence + counter; last block computes the loss (volatile reads).
// ---------------------------------------------------------------------------
__global__ __launch_bounds__(256, 3) void gemm_colsum_kernel(
    const unsigned char* __restrict__ Cn8,   // contrast rows -> sim rows i
    const unsigned char* __restrict__ An8,   // anchor rows   -> sim cols j
    float* __restrict__ colsum, const float* __restrict__ diag,
    float* __restrict__ out, unsigned int* __restrict__ counter) {
  __shared__ __align__(16) unsigned char lds[32768];
  __shared__ unsigned int isLast;
  __shared__ float red[4];

  const int tid  = threadIdx.x;
  const int lane = tid & 63;
  const int w    = tid >> 6;      // 4 waves
  const int wr   = w >> 1;        // i-half: 64 rows
  const int wc   = w & 1;         // j-half within a 64-col jtile: 32 cols

  const int jgroup = blockIdx.x & 15;
  const int itile  = blockIdx.x >> 4;
  const int i0 = itile * 128;
  const int j0 = jgroup * 512;

  // staging geometry (16-row rounds): row sr, phys slot tid&15 holds
  // logical slot pl = (tid&15) ^ (sr&7)   [involution phys = log ^ (row&7)]
  const int sr = tid >> 4;
  const int pl = (tid & 15) ^ (sr & 7);
  const unsigned char* gC = Cn8 + (size_t)(i0 + sr) * DIM + pl * 16;
  const unsigned char* gA = An8 + (size_t)(j0 + sr) * DIM + pl * 16;

  // ---- Phase 1: C-panel (32 KB), then capture af and free the LDS.
#pragma unroll
  for (int r = 0; r < 8; ++r)
    gload_lds16(gC + (size_t)(r * 16) * DIM, &lds[0] + r * 4096 + w * 1024);
  asm volatile("s_waitcnt vmcnt(0)" ::: "memory");
  __builtin_amdgcn_sched_barrier(0);
  __builtin_amdgcn_s_barrier();

  const int q  = lane >> 4;
  const int rb = lane & 15;
  const int SC = 0x7F7F7F7F;               // e8m0 127 -> scale 1.0

  i32x8 af[4][2];                          // C fragments held in regs
#pragma unroll
  for (int m = 0; m < 4; ++m) {
    const int r = wr * 64 + m * 16 + rb;
#pragma unroll
    for (int W = 0; W < 2; ++W) {
      const int s0 = (W * 8 + q * 2)     ^ (r & 7);
      const int s1 = (W * 8 + q * 2 + 1) ^ (r & 7);
      union { i32x4 h[2]; i32x8 v; } u;
      u.h[0] = *(const i32x4*)(&lds[0] + r * 256 + s0 * 16);
      u.h[1] = *(const i32x4*)(&lds[0] + r * 256 + s1 * 16);
      af[m][W] = u.v;
    }
  }
  asm volatile("s_waitcnt lgkmcnt(0)" ::: "memory");
  __builtin_amdgcn_sched_barrier(0);
  __builtin_amdgcn_s_barrier();            // C LDS now dead -> reuse for A
  __builtin_amdgcn_sched_barrier(0);

  // ---- Phase 2: A dbuf in the same 32 KB.
  auto stageA = [&](int jj, int buf) {     // 16 KB: 4 rounds x 16 rows
#pragma unroll
    for (int r = 0; r < 4; ++r)
      gload_lds16(gA + (size_t)(jj * 64 + r * 16) * DIM,
                  &lds[0] + buf * 16384 + r * 4096 + w * 1024);
  };
  stageA(0, 0);
  stageA(1, 1);

#pragma unroll
  for (int jj = 0; jj < 8; ++jj) {
    const int b = jj & 1;
    // outstanding at entry (per wave, incl. 2 atomics/jtile):
    // jj0: A0,A1 -> wait A0: 4.  jj1: A1,A2,at0x2 -> wait A1: 6.
    // jj2-6: A(jj),at(jj-2)x2,A(jj+1),at(jj-1)x2 -> 8.  jj7: at5x2,at6x2 -> 4.
    if (jj == 0)      asm volatile("s_waitcnt vmcnt(4)" ::: "memory");
    else if (jj == 1) asm volatile("s_waitcnt vmcnt(6)" ::: "memory");
    else if (jj == 7) asm volatile("s_waitcnt vmcnt(4)" ::: "memory");
    else              asm volatile("s_waitcnt vmcnt(8)" ::: "memory");
    __builtin_amdgcn_sched_barrier(0);
    __builtin_amdgcn_s_barrier();          // A(jj) visible to all waves

    i32x8 bf[2][2];
#pragma unroll
    for (int n = 0; n < 2; ++n) {
      const int r = wc * 32 + n * 16 + rb;
#pragma unroll
      for (int W = 0; W < 2; ++W) {
        const int s0 = (W * 8 + q * 2)     ^ (r & 7);
        const int s1 = (W * 8 + q * 2 + 1) ^ (r & 7);
        union { i32x4 h[2]; i32x8 v; } u;
        u.h[0] = *(const i32x4*)(&lds[0] + b * 16384 + r * 256 + s0 * 16);
        u.h[1] = *(const i32x4*)(&lds[0] + b * 16384 + r * 256 + s1 * 16);
        bf[n][W] = u.v;
      }
    }
    asm volatile("s_waitcnt lgkmcnt(0)" ::: "memory");
    __builtin_amdgcn_sched_barrier(0);     // rule #18
    __builtin_amdgcn_s_barrier();          // buf b fully consumed
    __builtin_amdgcn_sched_barrier(0);

    if (jj < 6) stageA(jj + 2, b);         // prefetch 2 ahead into freed buf
    __builtin_amdgcn_sched_barrier(0);

    f32x4 acc[4][2] = {};
    __builtin_amdgcn_s_setprio(1);
#pragma unroll
    for (int m = 0; m < 4; ++m)
#pragma unroll
      for (int n = 0; n < 2; ++n)
#pragma unroll
        for (int W = 0; W < 2; ++W)
          acc[m][n] = __builtin_amdgcn_mfma_scale_f32_16x16x128_f8f6f4(
              af[m][W], bf[n][W], acc[m][n], 0, 0, 0, SC, 0, SC);
    __builtin_amdgcn_s_setprio(0);
    __builtin_amdgcn_sched_barrier(0);

    // col partials over this wave's 64 i-rows; C/D layout:
    // col = lane&15, row = (lane>>4)*4 + reg (m89/m121).
#pragma unroll
    for (int n = 0; n < 2; ++n) {
      float s = 0.f;
#pragma unroll
      for (int m = 0; m < 4; ++m) {
        const f32x4 v = acc[m][n];
        s += __expf(v[0]) + __expf(v[1]) + __expf(v[2]) + __expf(v[3]);
      }
      s += __shfl_xor(s, 16);
      s += __shfl_xor(s, 32);
      if (lane < 16)
        atomicAdd(&colsum[j0 + jj * 64 + wc * 32 + n * 16 + lane], s);
    }
    __builtin_amdgcn_sched_barrier(0);
  }

  // ---- Tail: last block finalizes the loss.
  __threadfence();                         // drain this block's atomics
  __syncthreads();
  if (tid == 0) isLast = (atomicAdd(counter, 1u) == (unsigned)(gridDim.x - 1));
  __syncthreads();
  if (isLast) {
    __threadfence();
    volatile const float* cs = colsum;     // bypass L1 staleness
    float s = 0.f;
    for (int j = tid; j < BROWS; j += 256) s += logf(cs[j]) - diag[j];
#pragma unroll
    for (int o = 32; o > 0; o >>= 1) s += __shfl_down(s, o);
    if ((tid & 63) == 0) red[tid >> 6] = s;
    __syncthreads();
    if (tid == 0) out[0] = red[0] + red[1] + red[2] + red[3];
  }
}

// ---------------------------------------------------------------------------
// ws layout (~4.1 MB):
//   [0, 2MiB)            Cn8 fp8 [8192*256]
//   [2MiB, 4MiB)         An8 fp8 [8192*256]
//   [4MiB, +32KiB)       colsum f32 [8192]
//   [4MiB+32K, +32KiB)   diag   f32 [8192]
//   [4MiB+64K, +4B)      counter u32
// ---------------------------------------------------------------------------
extern "C" void kernel_launch(void* const* d_in, const int* in_sizes, int n_in,
                              void* d_out, int out_size, void* d_ws, size_t ws_size,
                              hipStream_t stream) {
  const float* E1 = (const float*)d_in[0];   // encoder_embedding1 -> anchors
  const float* E2 = (const float*)d_in[1];   // encoder_embedding2 -> contrast
  char* ws = (char*)d_ws;
  unsigned char* Cn8 = (unsigned char*)(ws);
  unsigned char* An8 = (unsigned char*)(ws + (size_t)2 * 1024 * 1024);
  float* colsum = (float*)(ws + (size_t)4 * 1024 * 1024);
  float* diag   = (float*)(ws + (size_t)4 * 1024 * 1024 + 32 * 1024);
  unsigned int* counter = (unsigned int*)(ws + (size_t)4 * 1024 * 1024 + 64 * 1024);
  float* out = (float*)d_out;

  prep_kernel<<<BROWS / 4, 256, 0, stream>>>(E1, E2, An8, Cn8, diag, colsum, counter);
  gemm_colsum_kernel<<<64 * 16, 256, 0, stream>>>(Cn8, An8, colsum, diag, out, counter);
}

// Round 16
// 107.027 us; speedup vs baseline: 1.0475x; 1.0475x over previous
//
#include <hip/hip_runtime.h>
#include <hip/hip_bf16.h>
#include <hip/hip_fp8.h>

// AlignConLoss: loss = sum_j [ log(sum_i exp(cn_i . an_j)) - cn_j . an_j ]
// B = 8192, D = 256, fp32 inputs, scalar fp32 out. sim in [-1,1] -> no max.
//
// R15 -> R16: REVERT to the verbatim R11 gemm (best measured, 46.1us total;
// launch_bounds(256,2), separate 64KB LDS, no VGPR cap -> no spill). R15's
// launch_bounds(256,3) capped VGPR at 72 < the ~116 live -> af spilled to
// scratch, reloaded 8x/block = ~0.5GB scratch traffic = 112us. Keep ONE
// R14 lever: finalize fused into gemm's last block (counter + threadfence);
// counter zeroed by prep. MX-fp8 mfma_scale 16x16x128 (scale=1.0); swizzle
// involution phys16B = log ^ (row&7) both sides (absmax-0-verified).

#define BROWS 8192
#define DIM   256

typedef int   i32x4 __attribute__((ext_vector_type(4)));
typedef int   i32x8 __attribute__((ext_vector_type(8)));
typedef float f32x4 __attribute__((ext_vector_type(4)));

__device__ __forceinline__ void gload_lds16(const void* g, void* l) {
  __builtin_amdgcn_global_load_lds(
      (const __attribute__((address_space(1))) unsigned int*)g,
      (__attribute__((address_space(3))) unsigned int*)l, 16, 0, 0);
}

__device__ __forceinline__ unsigned char to_e4m3(float v) {
  __hip_fp8_e4m3 t(v);
  return *reinterpret_cast<unsigned char*>(&t);
}

// ---------------------------------------------------------------------------
// Kernel 1: per-row L2 norms -> fp8 e4m3 normalized An/Cn; exact fp32 diag.
// One wave per row. Blocks 0..31 zero colsum; block 0 zeroes the counter.
// ---------------------------------------------------------------------------
__global__ __launch_bounds__(256) void prep_kernel(
    const float* __restrict__ E1, const float* __restrict__ E2,
    unsigned char* __restrict__ An8, unsigned char* __restrict__ Cn8,
    float* __restrict__ diag, float* __restrict__ colsum,
    unsigned int* __restrict__ counter) {
  if (blockIdx.x < 32) colsum[blockIdx.x * 256 + threadIdx.x] = 0.f;
  if (blockIdx.x == 0 && threadIdx.x == 0) counter[0] = 0u;

  const int w    = threadIdx.x >> 6;
  const int lane = threadIdx.x & 63;
  const int row  = blockIdx.x * 4 + w;
  const size_t base = (size_t)row * DIM + lane * 4;

  const float4 a = *(const float4*)(E1 + base);
  const float4 c = *(const float4*)(E2 + base);

  float sa  = a.x*a.x + a.y*a.y + a.z*a.z + a.w*a.w;
  float sc  = c.x*c.x + c.y*c.y + c.z*c.z + c.w*c.w;
  float sac = a.x*c.x + a.y*c.y + a.z*c.z + a.w*c.w;
#pragma unroll
  for (int o = 32; o > 0; o >>= 1) {
    sa  += __shfl_down(sa,  o);
    sc  += __shfl_down(sc,  o);
    sac += __shfl_down(sac, o);
  }
  const float inva = 1.0f / fmaxf(sqrtf(__shfl(sa, 0)), 1e-8f);
  const float invc = 1.0f / fmaxf(sqrtf(__shfl(sc, 0)), 1e-8f);

  uchar4 pa, pc;
  pa.x = to_e4m3(a.x * inva); pa.y = to_e4m3(a.y * inva);
  pa.z = to_e4m3(a.z * inva); pa.w = to_e4m3(a.w * inva);
  pc.x = to_e4m3(c.x * invc); pc.y = to_e4m3(c.y * invc);
  pc.z = to_e4m3(c.z * invc); pc.w = to_e4m3(c.w * invc);
  *(uchar4*)(An8 + base) = pa;
  *(uchar4*)(Cn8 + base) = pc;
  if (lane == 0) diag[row] = sac * inva * invc;
}

// ---------------------------------------------------------------------------
// Kernel 2: verbatim R11 structure. Block = 128 i x 512 j (8 jtiles of 64),
// grid = 64 x 16 = 1024. C-panel (32 KB) staged once, af in 64 VGPR;
// A-panels (16 KB) double-buffered, counted-vmcnt {jj0:4, jj1:6, jj2-6:8,
// jj7:4}. 4 waves (wr,wc) 2x2: 64 i-rows x 32 j-cols per jtile.
// Tail: threadfence + counter; last block computes the loss.
// ---------------------------------------------------------------------------
__global__ __launch_bounds__(256, 2) void gemm_colsum_kernel(
    const unsigned char* __restrict__ Cn8,   // contrast rows -> sim rows i
    const unsigned char* __restrict__ An8,   // anchor rows   -> sim cols j
    float* __restrict__ colsum, const float* __restrict__ diag,
    float* __restrict__ out, unsigned int* __restrict__ counter) {
  __shared__ __align__(16) unsigned char ldsC[32768];      // [128 rows][256 B]
  __shared__ __align__(16) unsigned char ldsA[2][16384];   // [buf][64 r][256 B]
  __shared__ unsigned int isLast;
  __shared__ float red[4];

  const int tid  = threadIdx.x;
  const int lane = tid & 63;
  const int w    = tid >> 6;      // 4 waves
  const int wr   = w >> 1;        // i-half: 64 rows
  const int wc   = w & 1;         // j-half within a 64-col jtile: 32 cols

  const int jgroup = blockIdx.x & 15;
  const int itile  = blockIdx.x >> 4;
  const int i0 = itile * 128;
  const int j0 = jgroup * 512;

  // staging geometry (16-row rounds): row sr, phys slot tid&15 holds
  // logical slot pl = (tid&15) ^ (sr&7)  [involution phys = log ^ (row&7)]
  const int sr = tid >> 4;
  const int pl = (tid & 15) ^ (sr & 7);
  const unsigned char* gC = Cn8 + (size_t)(i0 + sr) * DIM + pl * 16;
  const unsigned char* gA = An8 + (size_t)(j0 + sr) * DIM + pl * 16;

  auto stageA = [&](int jj, int buf) {     // 16 KB: 4 rounds x 16 rows
#pragma unroll
    for (int r = 0; r < 4; ++r)
      gload_lds16(gA + (size_t)(jj * 64 + r * 16) * DIM,
                  &ldsA[buf][0] + r * 4096 + w * 1024);
  };

#pragma unroll
  for (int r = 0; r < 8; ++r)              // C-panel: 8 rounds x 16 rows
    gload_lds16(gC + (size_t)(r * 16) * DIM, &ldsC[0] + r * 4096 + w * 1024);
  stageA(0, 0);
  stageA(1, 1);

  asm volatile("s_waitcnt vmcnt(8)" ::: "memory");   // C landed; A0,A1 fly
  __builtin_amdgcn_sched_barrier(0);
  __builtin_amdgcn_s_barrier();

  const int q  = lane >> 4;
  const int rb = lane & 15;
  const int SC = 0x7F7F7F7F;               // e8m0 127 -> scale 1.0

  i32x8 af[4][2];                          // C-panel fragments held in regs
#pragma unroll
  for (int m = 0; m < 4; ++m) {
    const int r = wr * 64 + m * 16 + rb;
#pragma unroll
    for (int W = 0; W < 2; ++W) {
      const int s0 = (W * 8 + q * 2)     ^ (r & 7);
      const int s1 = (W * 8 + q * 2 + 1) ^ (r & 7);
      union { i32x4 h[2]; i32x8 v; } u;
      u.h[0] = *(const i32x4*)(&ldsC[0] + r * 256 + s0 * 16);
      u.h[1] = *(const i32x4*)(&ldsC[0] + r * 256 + s1 * 16);
      af[m][W] = u.v;
    }
  }
  asm volatile("s_waitcnt lgkmcnt(0)" ::: "memory");
  __builtin_amdgcn_sched_barrier(0);

#pragma unroll
  for (int jj = 0; jj < 8; ++jj) {
    const int b = jj & 1;
    // outstanding at entry (per wave, incl. 2 atomics/jtile):
    // jj0: A0,A1 -> wait A0: 4.  jj1: A1,A2,at0x2 -> wait A1: 6.
    // jj2-6: A(jj),at(jj-2)x2,A(jj+1),at(jj-1)x2 -> 8.  jj7: at5x2,at6x2 -> 4.
    if (jj == 0)      asm volatile("s_waitcnt vmcnt(4)" ::: "memory");
    else if (jj == 1) asm volatile("s_waitcnt vmcnt(6)" ::: "memory");
    else if (jj == 7) asm volatile("s_waitcnt vmcnt(4)" ::: "memory");
    else              asm volatile("s_waitcnt vmcnt(8)" ::: "memory");
    __builtin_amdgcn_sched_barrier(0);
    __builtin_amdgcn_s_barrier();          // A(jj) visible to all waves

    i32x8 bf[2][2];                        // capture full A-tile to regs
#pragma unroll
    for (int n = 0; n < 2; ++n) {
      const int r = wc * 32 + n * 16 + rb;
#pragma unroll
      for (int W = 0; W < 2; ++W) {
        const int s0 = (W * 8 + q * 2)     ^ (r & 7);
        const int s1 = (W * 8 + q * 2 + 1) ^ (r & 7);
        union { i32x4 h[2]; i32x8 v; } u;
        u.h[0] = *(const i32x4*)(&ldsA[b][0] + r * 256 + s0 * 16);
        u.h[1] = *(const i32x4*)(&ldsA[b][0] + r * 256 + s1 * 16);
        bf[n][W] = u.v;
      }
    }
    asm volatile("s_waitcnt lgkmcnt(0)" ::: "memory");
    __builtin_amdgcn_sched_barrier(0);     // rule #18
    __builtin_amdgcn_s_barrier();          // buf b fully consumed
    __builtin_amdgcn_sched_barrier(0);

    if (jj < 6) stageA(jj + 2, b);         // prefetch 2 ahead into freed buf
    __builtin_amdgcn_sched_barrier(0);

    f32x4 acc[4][2] = {};
    __builtin_amdgcn_s_setprio(1);
#pragma unroll
    for (int m = 0; m < 4; ++m)
#pragma unroll
      for (int n = 0; n < 2; ++n)
#pragma unroll
        for (int W = 0; W < 2; ++W)
          acc[m][n] = __builtin_amdgcn_mfma_scale_f32_16x16x128_f8f6f4(
              af[m][W], bf[n][W], acc[m][n], 0, 0, 0, SC, 0, SC);
    __builtin_amdgcn_s_setprio(0);
    __builtin_amdgcn_sched_barrier(0);

    // col partials over this wave's 64 i-rows; C/D layout:
    // col = lane&15, row = (lane>>4)*4 + reg (m89/m121).
#pragma unroll
    for (int n = 0; n < 2; ++n) {
      float s = 0.f;
#pragma unroll
      for (int m = 0; m < 4; ++m) {
        const f32x4 v = acc[m][n];
        s += __expf(v[0]) + __expf(v[1]) + __expf(v[2]) + __expf(v[3]);
      }
      s += __shfl_xor(s, 16);
      s += __shfl_xor(s, 32);
      if (lane < 16)
        atomicAdd(&colsum[j0 + jj * 64 + wc * 32 + n * 16 + lane], s);
    }
    __builtin_amdgcn_sched_barrier(0);
  }

  // ---- Tail: last block finalizes the loss.
  __threadfence();                         // drain this block's atomics
  __syncthreads();
  if (tid == 0) isLast = (atomicAdd(counter, 1u) == (unsigned)(gridDim.x - 1));
  __syncthreads();
  if (isLast) {
    __threadfence();
    volatile const float* cs = colsum;     // bypass stale cached reads
    float s = 0.f;
    for (int j = tid; j < BROWS; j += 256) s += logf(cs[j]) - diag[j];
#pragma unroll
    for (int o = 32; o > 0; o >>= 1) s += __shfl_down(s, o);
    if ((tid & 63) == 0) red[tid >> 6] = s;
    __syncthreads();
    if (tid == 0) out[0] = red[0] + red[1] + red[2] + red[3];
  }
}

// ---------------------------------------------------------------------------
// ws layout (~4.1 MB):
//   [0, 2MiB)            Cn8 fp8 [8192*256]
//   [2MiB, 4MiB)         An8 fp8 [8192*256]
//   [4MiB, +32KiB)       colsum f32 [8192]
//   [4MiB+32K, +32KiB)   diag   f32 [8192]
//   [4MiB+64K, +4B)      counter u32
// ---------------------------------------------------------------------------
extern "C" void kernel_launch(void* const* d_in, const int* in_sizes, int n_in,
                              void* d_out, int out_size, void* d_ws, size_t ws_size,
                              hipStream_t stream) {
  const float* E1 = (const float*)d_in[0];   // encoder_embedding1 -> anchors
  const float* E2 = (const float*)d_in[1];   // encoder_embedding2 -> contrast
  char* ws = (char*)d_ws;
  unsigned char* Cn8 = (unsigned char*)(ws);
  unsigned char* An8 = (unsigned char*)(ws + (size_t)2 * 1024 * 1024);
  float* colsum = (float*)(ws + (size_t)4 * 1024 * 1024);
  float* diag   = (float*)(ws + (size_t)4 * 1024 * 1024 + 32 * 1024);
  unsigned int* counter = (unsigned int*)(ws + (size_t)4 * 1024 * 1024 + 64 * 1024);
  float* out = (float*)d_out;

  prep_kernel<<<BROWS / 4, 256, 0, stream>>>(E1, E2, An8, Cn8, diag, colsum, counter);
  gemm_colsum_kernel<<<64 * 16, 256, 0, stream>>>(Cn8, An8, colsum, diag, out, counter);
}

// Round 18
// 46.384 us; speedup vs baseline: 2.4171x; 2.3074x over previous
//
#include <hip/hip_runtime.h>
#include <hip/hip_bf16.h>
#include <hip/hip_fp8.h>

// AlignConLoss: loss = sum_j [ log(sum_i exp(cn_i . an_j)) - cn_j . an_j ]
// B = 8192, D = 256, fp32 inputs, scalar fp32 out. sim in [-1,1] -> no max.
//
// R16 -> R17: EXACT R11 restoration (best measured: 46.1us). R15/R16's
// fused finalize tail perturbed register allocation (VGPR_Count=88 < the
// 96+ needed for af+bf -> af pushed to AGPRs -> per-MFMA v_accvgpr_read
// chains -> MfmaUtil 5.7%, 107-112us, with NO spill traffic in FETCH).
// Lesson: keep cold heavyweight code OUT of the register-critical MFMA
// kernel. Separate finalize kernel restored.

#define BROWS 8192
#define DIM   256

typedef int   i32x4 __attribute__((ext_vector_type(4)));
typedef int   i32x8 __attribute__((ext_vector_type(8)));
typedef float f32x4 __attribute__((ext_vector_type(4)));

__device__ __forceinline__ void gload_lds16(const void* g, void* l) {
  __builtin_amdgcn_global_load_lds(
      (const __attribute__((address_space(1))) unsigned int*)g,
      (__attribute__((address_space(3))) unsigned int*)l, 16, 0, 0);
}

__device__ __forceinline__ unsigned char to_e4m3(float v) {
  __hip_fp8_e4m3 t(v);
  return *reinterpret_cast<unsigned char*>(&t);
}

// ---------------------------------------------------------------------------
// Kernel 1: per-row L2 norms -> fp8 e4m3 normalized An/Cn; exact fp32 diag.
// One wave per row. Blocks 0..31 also zero colsum[8192].
// ---------------------------------------------------------------------------
__global__ __launch_bounds__(256) void prep_kernel(
    const float* __restrict__ E1, const float* __restrict__ E2,
    unsigned char* __restrict__ An8, unsigned char* __restrict__ Cn8,
    float* __restrict__ diag, float* __restrict__ colsum) {
  if (blockIdx.x < 32) colsum[blockIdx.x * 256 + threadIdx.x] = 0.f;

  const int w    = threadIdx.x >> 6;
  const int lane = threadIdx.x & 63;
  const int row  = blockIdx.x * 4 + w;
  const size_t base = (size_t)row * DIM + lane * 4;

  const float4 a = *(const float4*)(E1 + base);
  const float4 c = *(const float4*)(E2 + base);

  float sa  = a.x*a.x + a.y*a.y + a.z*a.z + a.w*a.w;
  float sc  = c.x*c.x + c.y*c.y + c.z*c.z + c.w*c.w;
  float sac = a.x*c.x + a.y*c.y + a.z*c.z + a.w*c.w;
#pragma unroll
  for (int o = 32; o > 0; o >>= 1) {
    sa  += __shfl_down(sa,  o);
    sc  += __shfl_down(sc,  o);
    sac += __shfl_down(sac, o);
  }
  const float inva = 1.0f / fmaxf(sqrtf(__shfl(sa, 0)), 1e-8f);
  const float invc = 1.0f / fmaxf(sqrtf(__shfl(sc, 0)), 1e-8f);

  uchar4 pa, pc;
  pa.x = to_e4m3(a.x * inva); pa.y = to_e4m3(a.y * inva);
  pa.z = to_e4m3(a.z * inva); pa.w = to_e4m3(a.w * inva);
  pc.x = to_e4m3(c.x * invc); pc.y = to_e4m3(c.y * invc);
  pc.z = to_e4m3(c.z * invc); pc.w = to_e4m3(c.w * invc);
  *(uchar4*)(An8 + base) = pa;
  *(uchar4*)(Cn8 + base) = pc;
  if (lane == 0) diag[row] = sac * inva * invc;
}

// ---------------------------------------------------------------------------
// Kernel 2 (exact R11): block = 128 i x 512 j (8 jtiles of 64), MX-fp8
// mfma_scale 16x16x128 (scale=1.0). Grid = 64 itiles x 16 jgroups = 1024.
// C-panel (32 KB) staged once, fragments held in 64 VGPR. A-panels (16 KB)
// double-buffered, counted-vmcnt {jj0:4, jj1:6, jj2-6:8, jj7:4}. 4 waves
// (wr,wc) 2x2: 64 i-rows x 32 j-cols per jtile. LDS 64 KB -> 2 blocks/CU.
// ---------------------------------------------------------------------------
__global__ __launch_bounds__(256, 2) void gemm_colsum_kernel(
    const unsigned char* __restrict__ Cn8,   // contrast rows -> sim rows i
    const unsigned char* __restrict__ An8,   // anchor rows   -> sim cols j
    float* __restrict__ colsum) {
  __shared__ __align__(16) unsigned char ldsC[32768];      // [128 rows][256 B]
  __shared__ __align__(16) unsigned char ldsA[2][16384];   // [buf][64 r][256 B]

  const int tid  = threadIdx.x;
  const int lane = tid & 63;
  const int w    = tid >> 6;      // 4 waves
  const int wr   = w >> 1;        // i-half: 64 rows
  const int wc   = w & 1;         // j-half within a 64-col jtile: 32 cols

  const int jgroup = blockIdx.x & 15;
  const int itile  = blockIdx.x >> 4;
  const int i0 = itile * 128;
  const int j0 = jgroup * 512;

  // staging geometry (per 16-row round): row sr, phys slot tid&15 holds
  // logical slot pl = (tid&15) ^ (sr&7).
  const int sr = tid >> 4;
  const int pl = (tid & 15) ^ (sr & 7);
  const unsigned char* gC = Cn8 + (size_t)(i0 + sr) * DIM + pl * 16;
  const unsigned char* gA = An8 + (size_t)(j0 + sr) * DIM + pl * 16;

  auto stageA = [&](int jj, int buf) {     // 16 KB: 4 rounds x 16 rows
#pragma unroll
    for (int r = 0; r < 4; ++r)
      gload_lds16(gA + (size_t)(jj * 64 + r * 16) * DIM,
                  &ldsA[buf][0] + r * 4096 + w * 1024);
  };

#pragma unroll
  for (int r = 0; r < 8; ++r)              // C-panel: 8 rounds x 16 rows
    gload_lds16(gC + (size_t)(r * 16) * DIM, &ldsC[0] + r * 4096 + w * 1024);
  stageA(0, 0);
  stageA(1, 1);

  asm volatile("s_waitcnt vmcnt(8)" ::: "memory");   // C landed; A0,A1 fly
  __builtin_amdgcn_sched_barrier(0);
  __builtin_amdgcn_s_barrier();

  const int q  = lane >> 4;
  const int rb = lane & 15;
  const int SC = 0x7F7F7F7F;               // e8m0 127 -> scale 1.0

  i32x8 af[4][2];                          // C-panel fragments, held in regs
#pragma unroll
  for (int m = 0; m < 4; ++m) {
    const int r = wr * 64 + m * 16 + rb;
#pragma unroll
    for (int W = 0; W < 2; ++W) {
      const int s0 = (W * 8 + q * 2)     ^ (r & 7);
      const int s1 = (W * 8 + q * 2 + 1) ^ (r & 7);
      union { i32x4 h[2]; i32x8 v; } u;
      u.h[0] = *(const i32x4*)(&ldsC[0] + r * 256 + s0 * 16);
      u.h[1] = *(const i32x4*)(&ldsC[0] + r * 256 + s1 * 16);
      af[m][W] = u.v;
    }
  }
  asm volatile("s_waitcnt lgkmcnt(0)" ::: "memory");
  __builtin_amdgcn_sched_barrier(0);

#pragma unroll
  for (int jj = 0; jj < 8; ++jj) {
    const int b = jj & 1;
    if (jj == 0)      asm volatile("s_waitcnt vmcnt(4)" ::: "memory");
    else if (jj == 1) asm volatile("s_waitcnt vmcnt(6)" ::: "memory");
    else if (jj == 7) asm volatile("s_waitcnt vmcnt(4)" ::: "memory");
    else              asm volatile("s_waitcnt vmcnt(8)" ::: "memory");
    __builtin_amdgcn_sched_barrier(0);
    __builtin_amdgcn_s_barrier();          // A(jj) visible to all waves

    i32x8 bf[2][2];                        // capture full A-tile to regs
#pragma unroll
    for (int n = 0; n < 2; ++n) {
      const int r = wc * 32 + n * 16 + rb;
#pragma unroll
      for (int W = 0; W < 2; ++W) {
        const int s0 = (W * 8 + q * 2)     ^ (r & 7);
        const int s1 = (W * 8 + q * 2 + 1) ^ (r & 7);
        union { i32x4 h[2]; i32x8 v; } u;
        u.h[0] = *(const i32x4*)(&ldsA[b][0] + r * 256 + s0 * 16);
        u.h[1] = *(const i32x4*)(&ldsA[b][0] + r * 256 + s1 * 16);
        bf[n][W] = u.v;
      }
    }
    asm volatile("s_waitcnt lgkmcnt(0)" ::: "memory");
    __builtin_amdgcn_sched_barrier(0);     // rule #18
    __builtin_amdgcn_s_barrier();          // buf b fully consumed
    __builtin_amdgcn_sched_barrier(0);

    if (jj < 6) stageA(jj + 2, b);         // prefetch 2 ahead into freed buf
    __builtin_amdgcn_sched_barrier(0);

    f32x4 acc[4][2] = {};
    __builtin_amdgcn_s_setprio(1);
#pragma unroll
    for (int m = 0; m < 4; ++m)
#pragma unroll
      for (int n = 0; n < 2; ++n)
#pragma unroll
        for (int W = 0; W < 2; ++W)
          acc[m][n] = __builtin_amdgcn_mfma_scale_f32_16x16x128_f8f6f4(
              af[m][W], bf[n][W], acc[m][n], 0, 0, 0, SC, 0, SC);
    __builtin_amdgcn_s_setprio(0);
    __builtin_amdgcn_sched_barrier(0);

    // Epilogue: col partials over this wave's 64 i-rows; C/D layout:
    // col = lane&15, row = (lane>>4)*4 + reg (m89/m121).
#pragma unroll
    for (int n = 0; n < 2; ++n) {
      float s = 0.f;
#pragma unroll
      for (int m = 0; m < 4; ++m) {
        const f32x4 v = acc[m][n];
        s += __expf(v[0]) + __expf(v[1]) + __expf(v[2]) + __expf(v[3]);
      }
      s += __shfl_xor(s, 16);
      s += __shfl_xor(s, 32);
      if (lane < 16)
        atomicAdd(&colsum[j0 + jj * 64 + wc * 32 + n * 16 + lane], s);
    }
    __builtin_amdgcn_sched_barrier(0);
  }
}

// ---------------------------------------------------------------------------
// Kernel 3: loss = sum_j log(colsum[j]) - diag[j].  Single block.
// ---------------------------------------------------------------------------
__global__ __launch_bounds__(256) void finalize_kernel(
    const float* __restrict__ colsum, const float* __restrict__ diag,
    float* __restrict__ out) {
  const int t = threadIdx.x;
  float s = 0.f;
  for (int j = t; j < BROWS; j += 256) s += logf(colsum[j]) - diag[j];
#pragma unroll
  for (int o = 32; o > 0; o >>= 1) s += __shfl_down(s, o);
  __shared__ float red[4];
  if ((t & 63) == 0) red[t >> 6] = s;
  __syncthreads();
  if (t == 0) out[0] = red[0] + red[1] + red[2] + red[3];
}

// ---------------------------------------------------------------------------
// ws layout (~4.07 MB):
//   [0, 2MiB)            Cn8 fp8 [8192*256]
//   [2MiB, 4MiB)         An8 fp8 [8192*256]
//   [4MiB, +32KiB)       colsum f32 [8192]
//   [4MiB+32K, +32KiB)   diag   f32 [8192]
// ---------------------------------------------------------------------------
extern "C" void kernel_launch(void* const* d_in, const int* in_sizes, int n_in,
                              void* d_out, int out_size, void* d_ws, size_t ws_size,
                              hipStream_t stream) {
  const float* E1 = (const float*)d_in[0];   // encoder_embedding1 -> anchors
  const float* E2 = (const float*)d_in[1];   // encoder_embedding2 -> contrast
  char* ws = (char*)d_ws;
  unsigned char* Cn8 = (unsigned char*)(ws);
  unsigned char* An8 = (unsigned char*)(ws + (size_t)2 * 1024 * 1024);
  float* colsum = (float*)(ws + (size_t)4 * 1024 * 1024);
  float* diag   = (float*)(ws + (size_t)4 * 1024 * 1024 + 32 * 1024);
  float* out = (float*)d_out;

  prep_kernel<<<BROWS / 4, 256, 0, stream>>>(E1, E2, An8, Cn8, diag, colsum);
  gemm_colsum_kernel<<<64 * 16, 256, 0, stream>>>(Cn8, An8, colsum);
  finalize_kernel<<<1, 256, 0, stream>>>(colsum, diag, out);
}